// Round 7
// baseline (248.380 us; speedup 1.0000x reference)
//
#include <hip/hip_runtime.h>

#define NNODES 65536
#define FIN 1024
#define NEDGES 2097152
#define NB 64
#define G 256                 // buckets = dst>>8, also blocks in hist/scatter
#define CH (NEDGES / G)       // 8192 edges per scatter block
#define CAP 10240             // LDS staging capacity in ksortC (80 KB)
#define NR 20                 // reg-staged edges per thread in ksortC (20*512 = CAP)

// ================= pass 1: coarse histogram (dst>>8) per block =================
__global__ __launch_bounds__(256) void khist(const int* __restrict__ dst, int* __restrict__ counts) {
  __shared__ int hist[256];
  const int t = threadIdx.x, blk = blockIdx.x;
  hist[t] = 0;
  __syncthreads();
  const int base = blk * CH;
  for (int i = t; i < CH; i += 256) atomicAdd(&hist[((unsigned)dst[base + i]) >> 8], 1);
  __syncthreads();
  counts[t * G + blk] = hist[t];            // bucket-major, block-minor
}

// ================= fused exclusive scan over 65536 cells, one block =================
__global__ __launch_bounds__(1024) void kscan1(const int* __restrict__ in, int* __restrict__ out) {
  __shared__ int wsum[16];
  const int t = threadIdx.x;
  const int lane = t & 63, wid = t >> 6;
  int4 v[16];
  const int4* __restrict__ ip = (const int4*)(in + t * 64);
  int s = 0;
#pragma unroll
  for (int i = 0; i < 16; ++i) { v[i] = ip[i]; s += v[i].x + v[i].y + v[i].z + v[i].w; }
  int inc = s;
#pragma unroll
  for (int off = 1; off < 64; off <<= 1) {
    int o = __shfl_up(inc, off, 64);
    if (lane >= off) inc += o;
  }
  if (lane == 63) wsum[wid] = inc;
  __syncthreads();
  if (t < 16) {
    int w = wsum[t];
    int wi = w;
#pragma unroll
    for (int off = 1; off < 16; off <<= 1) {
      int o = __shfl_up(wi, off, 16);
      if (t >= off) wi += o;
    }
    wsum[t] = wi - w;                       // exclusive warp prefix
  }
  __syncthreads();
  int run = inc - s + wsum[wid];            // exclusive prefix of this thread's chunk
  int4* __restrict__ op = (int4*)(out + t * 64);
#pragma unroll
  for (int i = 0; i < 16; ++i) {
    int4 o4;
    o4.x = run; run += v[i].x;
    o4.y = run; run += v[i].y;
    o4.z = run; run += v[i].z;
    o4.w = run; run += v[i].w;
    op[i] = o4;
  }
}

// ================= pass 2: LDS-partitioned scatter into bucket-grouped tmp =================
__global__ __launch_bounds__(1024) void kscatter3(const int* __restrict__ src, const int* __restrict__ dst,
                                                  const float* __restrict__ ew, const int* __restrict__ ofs,
                                                  int2* __restrict__ tmp) {
  __shared__ int2 ent[CH];                  // 64 KB
  __shared__ int hist[256], excl[256], cursor[256], ldsofs[256], sh[256];
  const int t = threadIdx.x, blk = blockIdx.x;
  if (t < 256) { hist[t] = 0; ldsofs[t] = ofs[t * G + blk]; }
  __syncthreads();
  int sa[8], da[8]; float wa[8];
  const int base = blk * CH;
#pragma unroll
  for (int i = 0; i < 8; ++i) {
    const int e = base + t + i * 1024;
    sa[i] = src[e]; da[i] = dst[e]; wa[i] = ew[e];
    atomicAdd(&hist[((unsigned)da[i]) >> 8], 1);
  }
  __syncthreads();
  if (t < 256) sh[t] = hist[t];
  __syncthreads();
#pragma unroll
  for (int off = 1; off < 256; off <<= 1) {
    int a = (t < 256 && t >= off) ? sh[t - off] : 0;
    __syncthreads();
    if (t < 256) sh[t] += a;
    __syncthreads();
  }
  if (t < 256) { excl[t] = sh[t] - hist[t]; cursor[t] = sh[t] - hist[t]; }
  __syncthreads();
#pragma unroll
  for (int i = 0; i < 8; ++i) {
    const int b = ((unsigned)da[i]) >> 8;
    const int pos = atomicAdd(&cursor[b], 1);
    ent[pos] = make_int2((sa[i] & 0xFFFF) | ((da[i] & 255) << 16) | (b << 24), __float_as_int(wa[i]));
  }
  __syncthreads();
#pragma unroll
  for (int i = 0; i < 8; ++i) {
    const int idx = t + i * 1024;
    const int2 p = ent[idx];
    const int b = ((unsigned)p.x) >> 24;
    tmp[ldsofs[b] + (idx - excl[b])] = make_int2(p.x & 0x00FFFFFF, p.y);
  }
}

// ================= pass 3: per-bucket fine sort, single tmp read (reg-staged) =================
__global__ __launch_bounds__(512) void ksortC(const int2* __restrict__ tmp, const int* __restrict__ ofs,
                                              int2* __restrict__ csr, int* __restrict__ rs,
                                              int* __restrict__ cnt, float* __restrict__ dinv) {
  __shared__ int2 stg[CAP];                 // 80 KB
  __shared__ int hist[256], excl[256], cursor[256];
  __shared__ float degacc[256];
  const int t = threadIdx.x, b = blockIdx.x;
  const int base = ofs[b * G];
  const int end = (b == G - 1) ? NEDGES : ofs[(b + 1) * G];
  const int n = end - base;
  if (t < 256) { hist[t] = 0; degacc[t] = 0.f; }
  __syncthreads();
  int2 r[NR];
#pragma unroll
  for (int i = 0; i < NR; ++i) {
    const int idx = i * 512 + t;
    if (idx < n) r[i] = tmp[base + idx];
  }
#pragma unroll
  for (int i = 0; i < NR; ++i) {
    const int idx = i * 512 + t;
    if (idx < n) atomicAdd(&hist[(r[i].x >> 16) & 255], 1);
  }
  __syncthreads();
  if (t < 256) excl[t] = hist[t];
  __syncthreads();
#pragma unroll
  for (int off = 1; off < 256; off <<= 1) {
    int a = (t < 256 && t >= off) ? excl[t - off] : 0;
    __syncthreads();
    if (t < 256) excl[t] += a;
    __syncthreads();
  }
  if (t < 256) {
    const int e = excl[t] - hist[t];
    cursor[t] = e;
    rs[b * 256 + t] = base + e;
    cnt[b * 256 + t] = hist[t];
  }
  __syncthreads();
#pragma unroll
  for (int i = 0; i < NR; ++i) {
    const int idx = i * 512 + t;
    if (idx < n) {
      const int fine = (r[i].x >> 16) & 255;
      const int pos = atomicAdd(&cursor[fine], 1);
      const int2 rec = make_int2(r[i].x & 0xFFFF, r[i].y);
      if (pos < CAP) stg[pos] = rec;
      else csr[base + pos] = rec;           // statistically unreachable
      atomicAdd(&degacc[fine], __int_as_float(r[i].y));
    }
  }
  __syncthreads();
  if (t < 256) dinv[b * 256 + t] = rsqrtf(1.0f + degacc[t]);
  const int m = n < CAP ? n : CAP;
  for (int j = t; j < m; j += 512) csr[base + j] = stg[j];   // coalesced writeout
}

// ================= H1 = (x @ W1) * dinv[row]  (K-chunk 64, stride-68 LDS) =================
__global__ __launch_bounds__(256) void kgemm1(const float* __restrict__ x, const float* __restrict__ W1,
                                              const float* __restrict__ dinv, float* __restrict__ H1) {
  __shared__ float sx[64 * 68];             // 64 rows x 64 k, stride 68 (2-way free)
  __shared__ float sw[64 * 16];
  const int t = threadIdx.x;
  const int r = t >> 2, jg = t & 3;
  const int row0 = blockIdx.x * 64;
  float4 acc = make_float4(0.f, 0.f, 0.f, 0.f);
  for (int ch = 0; ch < 16; ++ch) {
    const int c0 = ch * 64;
#pragma unroll
    for (int i = 0; i < 4; ++i) {           // stage X: 1024 float4, coalesced
      const int v = t + i * 256;
      const int rr = v >> 4, cc = v & 15;
      *(float4*)&sx[rr * 68 + cc * 4] =
          *(const float4*)(x + (size_t)(row0 + rr) * FIN + c0 + cc * 4);
    }
    {                                       // stage W chunk: 256 float4, coalesced
      const int kk = t >> 2, c4 = t & 3;
      *(float4*)&sw[kk * 16 + c4 * 4] = *(const float4*)(W1 + (size_t)(c0 + kk) * 16 + c4 * 4);
    }
    __syncthreads();
#pragma unroll
    for (int k4 = 0; k4 < 16; ++k4) {
      const float4 xv = *(const float4*)&sx[r * 68 + k4 * 4];
      const float xs[4] = {xv.x, xv.y, xv.z, xv.w};
#pragma unroll
      for (int e = 0; e < 4; ++e) {
        const float4 w4 = *(const float4*)&sw[(k4 * 4 + e) * 16 + jg * 4];
        acc.x = fmaf(xs[e], w4.x, acc.x);
        acc.y = fmaf(xs[e], w4.y, acc.y);
        acc.z = fmaf(xs[e], w4.z, acc.z);
        acc.w = fmaf(xs[e], w4.w, acc.w);
      }
    }
    __syncthreads();
  }
  const float dn = dinv[row0 + r];
  acc.x *= dn; acc.y *= dn; acc.z *= dn; acc.w *= dn;
  *(float4*)(H1 + (size_t)(row0 + r) * 16 + jg * 4) = acc;
}

// ================= gather layer 1: agg(H1) -> relu -> @W2 -> H2 (scaled) =================
__global__ __launch_bounds__(256) void kgather1(const float* __restrict__ H1, const int* __restrict__ rs,
                                                const int* __restrict__ cnt, const int2* __restrict__ csr,
                                                const float* __restrict__ dinv,
                                                const float* __restrict__ W2, const float* __restrict__ b1,
                                                float* __restrict__ H2) {
  __shared__ float sh_t[4][16];
  const int tid = threadIdx.x, wv = tid >> 6, l = tid & 63;
  const int n = blockIdx.x * 4 + wv;
  const int f = l & 15, slot = l >> 4;
  const int beg = rs[n], len = cnt[n];
  float acc = 0.f;
  for (int j = slot; j < len; j += 4) {
    const int2 p = csr[beg + j];
    acc = fmaf(__int_as_float(p.y), H1[(size_t)p.x * 16 + f], acc);
  }
  acc += __shfl_xor(acc, 16, 64);
  acc += __shfl_xor(acc, 32, 64);
  if (slot == 0) {
    const float dn = dinv[n];
    float t = dn * (acc + H1[(size_t)n * 16 + f]) + b1[f];
    sh_t[wv][f] = t > 0.f ? t : 0.f;
  }
  __syncthreads();
  if (tid < 16) {
    const int w2 = tid >> 2, c = tid & 3;
    const int nn = blockIdx.x * 4 + w2;
    float s = 0.f;
#pragma unroll
    for (int ff = 0; ff < 16; ++ff) s = fmaf(sh_t[w2][ff], W2[ff * 4 + c], s);
    H2[(size_t)nn * 4 + c] = s * dinv[nn];
  }
}

// ================= gather layer 2: agg(H2) -> relu -> @W3 -> H3 (scaled) =================
__global__ __launch_bounds__(256) void kgather2(const float* __restrict__ H2, const int* __restrict__ rs,
                                                const int* __restrict__ cnt, const int2* __restrict__ csr,
                                                const float* __restrict__ dinv,
                                                const float* __restrict__ W3, const float* __restrict__ b2,
                                                float* __restrict__ H3) {
  const int tid = threadIdx.x, wv = tid >> 6, l = tid & 63;
  const int n = blockIdx.x * 4 + wv;
  const int f = l & 3, slot = l >> 2;
  const int beg = rs[n], len = cnt[n];
  float acc = 0.f;
  for (int j = slot; j < len; j += 16) {
    const int2 p = csr[beg + j];
    acc = fmaf(__int_as_float(p.y), H2[(size_t)p.x * 4 + f], acc);
  }
#pragma unroll
  for (int off = 4; off < 64; off <<= 1) acc += __shfl_xor(acc, off, 64);
  const float dn = dinv[n];
  float t = dn * (acc + H2[(size_t)n * 4 + f]) + b2[f];
  t = t > 0.f ? t : 0.f;
  float p = t * W3[f];
  p += __shfl_xor(p, 1, 64);
  p += __shfl_xor(p, 2, 64);
  if (l == 0) H3[n] = p * dn;
}

// ================= gather layer 3: agg(H3) -> relu -> flat (+ seed out with bias) ==========
__global__ __launch_bounds__(256) void kgather3(const float* __restrict__ H3, const int* __restrict__ rs,
                                                const int* __restrict__ cnt, const int2* __restrict__ csr,
                                                const float* __restrict__ dinv,
                                                const float* __restrict__ b3, float* __restrict__ flat,
                                                const float* __restrict__ bout, float* __restrict__ out) {
  const int tid = threadIdx.x, wv = tid >> 6, l = tid & 63;
  if (blockIdx.x == 0 && tid < NB) out[tid] = bout[tid];   // seed final accumulator
  const int n = blockIdx.x * 4 + wv;
  const int beg = rs[n], len = cnt[n];
  float acc = 0.f;
  for (int j = l; j < len; j += 64) {
    const int2 p = csr[beg + j];
    acc = fmaf(__int_as_float(p.y), H3[p.x], acc);
  }
#pragma unroll
  for (int off = 1; off < 64; off <<= 1) acc += __shfl_xor(acc, off, 64);
  if (l == 0) {
    const float dn = dinv[n];
    float t = dn * (acc + H3[n]) + b3[0];
    flat[n] = t > 0.f ? t : 0.f;
  }
}

// ================= final dense: out[b] += partial dot(flat, W_out[b,:]) =================
__global__ __launch_bounds__(256) void kfinal(const float* __restrict__ flat, const float* __restrict__ Wout,
                                              float* __restrict__ out) {
  const int b = blockIdx.x >> 2, q = blockIdx.x & 3;
  const float4* __restrict__ f4 = (const float4*)(flat) + q * 4096;
  const float4* __restrict__ w4 = (const float4*)(Wout + (size_t)b * NNODES) + q * 4096;
  float s = 0.f;
  for (int i = threadIdx.x; i < 4096; i += 256) {
    const float4 a = f4[i];
    const float4 wv = w4[i];
    s += a.x * wv.x + a.y * wv.y + a.z * wv.z + a.w * wv.w;
  }
#pragma unroll
  for (int off = 32; off; off >>= 1) s += __shfl_down(s, off, 64);
  __shared__ float red[4];
  if ((threadIdx.x & 63) == 0) red[threadIdx.x >> 6] = s;
  __syncthreads();
  if (threadIdx.x == 0) atomicAdd(&out[b], red[0] + red[1] + red[2] + red[3]);
}

extern "C" void kernel_launch(void* const* d_in, const int* in_sizes, int n_in,
                              void* d_out, int out_size, void* d_ws, size_t ws_size,
                              hipStream_t stream) {
  const float* x   = (const float*)d_in[0];
  const int*   A   = (const int*)d_in[1];
  const float* ew  = (const float*)d_in[2];
  const float* W1  = (const float*)d_in[3];
  const float* b1  = (const float*)d_in[4];
  const float* W2  = (const float*)d_in[5];
  const float* b2  = (const float*)d_in[6];
  const float* W3  = (const float*)d_in[7];
  const float* b3  = (const float*)d_in[8];
  const float* Wo  = (const float*)d_in[9];
  const float* bo  = (const float*)d_in[10];
  float* out = (float*)d_out;

  const int* src = A;
  const int* dst = A + NEDGES;

  // ---- workspace layout ----
  char* p = (char*)d_ws;
  float* dinv   = (float*)p; p += sizeof(float) * NNODES;
  int*   rsofs  = (int*)p;   p += sizeof(int) * NNODES;
  int*   cnt    = (int*)p;   p += sizeof(int) * NNODES;
  int*   counts = (int*)p;   p += sizeof(int) * 256 * G;
  int*   ofs    = (int*)p;   p += sizeof(int) * 256 * G;
  int2*  tmp    = (int2*)p;  p += sizeof(int2) * NEDGES;
  int2*  csr    = (int2*)p;  p += sizeof(int2) * NEDGES;
  float* H1     = (float*)p; p += sizeof(float) * (size_t)NNODES * 16;
  float* H2     = (float*)p; p += sizeof(float) * (size_t)NNODES * 4;
  float* H3     = (float*)p; p += sizeof(float) * NNODES;
  float* flat   = (float*)p; p += sizeof(float) * NNODES;

  // ---- CSR build (no global atomics, coalesced writes) ----
  khist<<<G, 256, 0, stream>>>(dst, counts);
  kscan1<<<1, 1024, 0, stream>>>(counts, ofs);
  kscatter3<<<G, 1024, 0, stream>>>(src, dst, ew, ofs, tmp);
  ksortC<<<G, 512, 0, stream>>>(tmp, ofs, csr, rsofs, cnt, dinv);

  // ---- network (scaled activations H = h * dinv, raw ew weights) ----
  kgemm1<<<NNODES / 64, 256, 0, stream>>>(x, W1, dinv, H1);
  kgather1<<<NNODES / 4, 256, 0, stream>>>(H1, rsofs, cnt, csr, dinv, W2, b1, H2);
  kgather2<<<NNODES / 4, 256, 0, stream>>>(H2, rsofs, cnt, csr, dinv, W3, b2, H3);
  kgather3<<<NNODES / 4, 256, 0, stream>>>(H3, rsofs, cnt, csr, dinv, b3, flat, bo, out);
  kfinal<<<NB * 4, 256, 0, stream>>>(flat, Wo, out);
}

// Round 8
// 239.312 us; speedup vs baseline: 1.0379x; 1.0379x over previous
//
#include <hip/hip_runtime.h>

#define NNODES 65536
#define FIN 1024
#define NEDGES 2097152
#define NB 64
#define G 256                 // buckets = dst>>8
#define CH (NEDGES / G)       // 8192 edges per scatter block
#define CAP 10240             // LDS staging capacity in ksortC (80 KB)
#define NR 20                 // reg-staged edges per thread in ksortC (20*512 = CAP)
#define GEMMB 512             // gemm blocks in fused kernel A

// ================= kernel A: fused  h1 = x@W1 (unscaled)  ∪  coarse histogram =================
__global__ __launch_bounds__(512) void khistgemm(const float* __restrict__ x, const float* __restrict__ W1,
                                                 float* __restrict__ h1, const int* __restrict__ dst,
                                                 int* __restrict__ counts) {
  __shared__ float sx[128 * 68];            // 128 rows x 64 k, stride 68
  __shared__ float sw[64 * 16];
  __shared__ int hist[256];
  const int t = threadIdx.x;
  if (blockIdx.x < GEMMB) {
    // ---- GEMM part: 128 rows per block ----
    const int r = t >> 2, jg = t & 3;
    const int row0 = blockIdx.x * 128;
    float4 acc = make_float4(0.f, 0.f, 0.f, 0.f);
    for (int ch = 0; ch < 16; ++ch) {
      const int c0 = ch * 64;
#pragma unroll
      for (int i = 0; i < 4; ++i) {         // stage X: 2048 float4, coalesced
        const int v = t + i * 512;
        const int rr = v >> 4, cc = v & 15;
        *(float4*)&sx[rr * 68 + cc * 4] =
            *(const float4*)(x + (size_t)(row0 + rr) * FIN + c0 + cc * 4);
      }
      if (t < 256) {                        // stage W chunk: 256 float4
        const int kk = t >> 2, c4 = t & 3;
        *(float4*)&sw[kk * 16 + c4 * 4] = *(const float4*)(W1 + (size_t)(c0 + kk) * 16 + c4 * 4);
      }
      __syncthreads();
#pragma unroll
      for (int k4 = 0; k4 < 16; ++k4) {
        const float4 xv = *(const float4*)&sx[r * 68 + k4 * 4];
        const float xs[4] = {xv.x, xv.y, xv.z, xv.w};
#pragma unroll
        for (int e = 0; e < 4; ++e) {
          const float4 w4 = *(const float4*)&sw[(k4 * 4 + e) * 16 + jg * 4];
          acc.x = fmaf(xs[e], w4.x, acc.x);
          acc.y = fmaf(xs[e], w4.y, acc.y);
          acc.z = fmaf(xs[e], w4.z, acc.z);
          acc.w = fmaf(xs[e], w4.w, acc.w);
        }
      }
      __syncthreads();
    }
    *(float4*)(h1 + (size_t)(row0 + r) * 16 + jg * 4) = acc;   // UNSCALED
  } else {
    // ---- histogram part ----
    const int blk = blockIdx.x - GEMMB;
    if (t < 256) hist[t] = 0;
    __syncthreads();
    const int base = blk * CH;
    for (int i = t; i < CH; i += 512) atomicAdd(&hist[((unsigned)dst[base + i]) >> 8], 1);
    __syncthreads();
    if (t < 256) counts[t * G + blk] = hist[t];   // bucket-major, block-minor
  }
}

// ================= kernel B: scatter with redundant in-block scan (no kscan launch) ==========
__global__ __launch_bounds__(1024) void kscatter3(const int* __restrict__ src, const int* __restrict__ dst,
                                                  const float* __restrict__ ew, const int* __restrict__ counts,
                                                  int2* __restrict__ tmp, int* __restrict__ bucketofs) {
  __shared__ int2 ent[CH];                  // 64 KB
  __shared__ int hist[256], excl[256], cursor[256], ldsofs[256], sh[256];
  __shared__ int wsum[16];
  const int t = threadIdx.x, blk = blockIdx.x;
  const int lane = t & 63, wid = t >> 6;

  // ---- redundant full scan of counts (65536 cells) in registers ----
  int4 v[16];
  {
    const int4* __restrict__ ip = (const int4*)(counts + t * 64);
    int s = 0;
#pragma unroll
    for (int i = 0; i < 16; ++i) { v[i] = ip[i]; s += v[i].x + v[i].y + v[i].z + v[i].w; }
    int inc = s;
#pragma unroll
    for (int off = 1; off < 64; off <<= 1) {
      int o = __shfl_up(inc, off, 64);
      if (lane >= off) inc += o;
    }
    if (lane == 63) wsum[wid] = inc;
    __syncthreads();
    if (t < 16) {
      int w = wsum[t];
      int wi = w;
#pragma unroll
      for (int off = 1; off < 16; off <<= 1) {
        int o = __shfl_up(wi, off, 16);
        if (t >= off) wi += o;
      }
      wsum[t] = wi - w;
    }
    __syncthreads();
    int run = inc - s + wsum[wid];          // global exclusive prefix at cell t*64
    const int j0 = (blk - t * 64) & 255;    // the one cell (if <64) belonging to this block
#pragma unroll
    for (int i = 0; i < 16; ++i) {
      const int vals[4] = {v[i].x, v[i].y, v[i].z, v[i].w};
#pragma unroll
      for (int q = 0; q < 4; ++q) {
        const int j = i * 4 + q;
        if (j == j0) {
          const int c = t * 64 + j;
          ldsofs[c >> 8] = run;             // global start of (bucket c>>8, blk) run
          hist[c >> 8] = vals[q];           // this block's count for that bucket
        }
        run += vals[q];
      }
    }
  }
  __syncthreads();
  if (blk == 0) {                           // publish bucket boundaries for ksortC
    if (t < 256) bucketofs[t] = ldsofs[t];
    if (t == 0) bucketofs[256] = NEDGES;
  }
  // ---- in-block exclusive scan of hist -> excl/cursor ----
  if (t < 256) sh[t] = hist[t];
  __syncthreads();
#pragma unroll
  for (int off = 1; off < 256; off <<= 1) {
    int a = (t < 256 && t >= off) ? sh[t - off] : 0;
    __syncthreads();
    if (t < 256) sh[t] += a;
    __syncthreads();
  }
  if (t < 256) { excl[t] = sh[t] - hist[t]; cursor[t] = sh[t] - hist[t]; }
  __syncthreads();
  // ---- load edges, LDS-partition, contiguous writeout ----
  int sa[8], da[8]; float wa[8];
  const int base = blk * CH;
#pragma unroll
  for (int i = 0; i < 8; ++i) {
    const int e = base + t + i * 1024;
    sa[i] = src[e]; da[i] = dst[e]; wa[i] = ew[e];
  }
#pragma unroll
  for (int i = 0; i < 8; ++i) {
    const int b = ((unsigned)da[i]) >> 8;
    const int pos = atomicAdd(&cursor[b], 1);
    ent[pos] = make_int2((sa[i] & 0xFFFF) | ((da[i] & 255) << 16) | (b << 24), __float_as_int(wa[i]));
  }
  __syncthreads();
#pragma unroll
  for (int i = 0; i < 8; ++i) {
    const int idx = t + i * 1024;
    const int2 p = ent[idx];
    const int b = ((unsigned)p.x) >> 24;
    tmp[ldsofs[b] + (idx - excl[b])] = make_int2(p.x & 0x00FFFFFF, p.y);
  }
}

// ================= kernel C: per-bucket fine sort (reg-staged single read) =================
__global__ __launch_bounds__(512) void ksortC(const int2* __restrict__ tmp, const int* __restrict__ bucketofs,
                                              int2* __restrict__ csr, int* __restrict__ rs,
                                              int* __restrict__ cnt, float* __restrict__ dinv) {
  __shared__ int2 stg[CAP];                 // 80 KB
  __shared__ int hist[256], excl[256], cursor[256];
  __shared__ float degacc[256];
  const int t = threadIdx.x, b = blockIdx.x;
  const int base = bucketofs[b];
  const int end = bucketofs[b + 1];
  const int n = end - base;
  if (t < 256) { hist[t] = 0; degacc[t] = 0.f; }
  __syncthreads();
  int2 r[NR];
#pragma unroll
  for (int i = 0; i < NR; ++i) {
    const int idx = i * 512 + t;
    if (idx < n) r[i] = tmp[base + idx];
  }
#pragma unroll
  for (int i = 0; i < NR; ++i) {
    const int idx = i * 512 + t;
    if (idx < n) atomicAdd(&hist[(r[i].x >> 16) & 255], 1);
  }
  __syncthreads();
  if (t < 256) excl[t] = hist[t];
  __syncthreads();
#pragma unroll
  for (int off = 1; off < 256; off <<= 1) {
    int a = (t < 256 && t >= off) ? excl[t - off] : 0;
    __syncthreads();
    if (t < 256) excl[t] += a;
    __syncthreads();
  }
  if (t < 256) {
    const int e = excl[t] - hist[t];
    cursor[t] = e;
    rs[b * 256 + t] = base + e;
    cnt[b * 256 + t] = hist[t];
  }
  __syncthreads();
#pragma unroll
  for (int i = 0; i < NR; ++i) {
    const int idx = i * 512 + t;
    if (idx < n) {
      const int fine = (r[i].x >> 16) & 255;
      const int pos = atomicAdd(&cursor[fine], 1);
      const int2 rec = make_int2(r[i].x & 0xFFFF, r[i].y);
      if (pos < CAP) stg[pos] = rec;
      else csr[base + pos] = rec;           // statistically unreachable
      atomicAdd(&degacc[fine], __int_as_float(r[i].y));
    }
  }
  __syncthreads();
  if (t < 256) dinv[b * 256 + t] = rsqrtf(1.0f + degacc[t]);
  const int m = n < CAP ? n : CAP;
  for (int j = t; j < m; j += 512) csr[base + j] = stg[j];   // coalesced writeout
}

// ================= gather layer 1: agg(dinv[s]*h1[s]) -> relu -> @W2 -> H2 (scaled) ==========
__global__ __launch_bounds__(256) void kgather1(const float* __restrict__ h1, const int* __restrict__ rs,
                                                const int* __restrict__ cnt, const int2* __restrict__ csr,
                                                const float* __restrict__ dinv,
                                                const float* __restrict__ W2, const float* __restrict__ b1,
                                                float* __restrict__ H2) {
  __shared__ float sh_t[4][16];
  const int tid = threadIdx.x, wv = tid >> 6, l = tid & 63;
  const int n = blockIdx.x * 4 + wv;
  const int f = l & 15, slot = l >> 4;
  const int beg = rs[n], len = cnt[n];
  float acc = 0.f;
  for (int j = slot; j < len; j += 4) {
    const int2 p = csr[beg + j];
    acc = fmaf(__int_as_float(p.y) * dinv[p.x], h1[(size_t)p.x * 16 + f], acc);
  }
  acc += __shfl_xor(acc, 16, 64);
  acc += __shfl_xor(acc, 32, 64);
  if (slot == 0) {
    const float dn = dinv[n];
    float t = dn * (acc + dn * h1[(size_t)n * 16 + f]) + b1[f];
    sh_t[wv][f] = t > 0.f ? t : 0.f;
  }
  __syncthreads();
  if (tid < 16) {
    const int w2 = tid >> 2, c = tid & 3;
    const int nn = blockIdx.x * 4 + w2;
    float s = 0.f;
#pragma unroll
    for (int ff = 0; ff < 16; ++ff) s = fmaf(sh_t[w2][ff], W2[ff * 4 + c], s);
    H2[(size_t)nn * 4 + c] = s * dinv[nn];
  }
}

// ================= gather layer 2: agg(H2) -> relu -> @W3 -> H3 (scaled) =================
__global__ __launch_bounds__(256) void kgather2(const float* __restrict__ H2, const int* __restrict__ rs,
                                                const int* __restrict__ cnt, const int2* __restrict__ csr,
                                                const float* __restrict__ dinv,
                                                const float* __restrict__ W3, const float* __restrict__ b2,
                                                float* __restrict__ H3) {
  const int tid = threadIdx.x, wv = tid >> 6, l = tid & 63;
  const int n = blockIdx.x * 4 + wv;
  const int f = l & 3, slot = l >> 2;
  const int beg = rs[n], len = cnt[n];
  float acc = 0.f;
  for (int j = slot; j < len; j += 16) {
    const int2 p = csr[beg + j];
    acc = fmaf(__int_as_float(p.y), H2[(size_t)p.x * 4 + f], acc);
  }
#pragma unroll
  for (int off = 4; off < 64; off <<= 1) acc += __shfl_xor(acc, off, 64);
  const float dn = dinv[n];
  float t = dn * (acc + H2[(size_t)n * 4 + f]) + b2[f];
  t = t > 0.f ? t : 0.f;
  float p = t * W3[f];
  p += __shfl_xor(p, 1, 64);
  p += __shfl_xor(p, 2, 64);
  if (l == 0) H3[n] = p * dn;
}

// ================= gather layer 3: agg(H3) -> relu -> flat (+ seed out with bias) ==========
__global__ __launch_bounds__(256) void kgather3(const float* __restrict__ H3, const int* __restrict__ rs,
                                                const int* __restrict__ cnt, const int2* __restrict__ csr,
                                                const float* __restrict__ dinv,
                                                const float* __restrict__ b3, float* __restrict__ flat,
                                                const float* __restrict__ bout, float* __restrict__ out) {
  const int tid = threadIdx.x, wv = tid >> 6, l = tid & 63;
  if (blockIdx.x == 0 && tid < NB) out[tid] = bout[tid];   // seed final accumulator
  const int n = blockIdx.x * 4 + wv;
  const int beg = rs[n], len = cnt[n];
  float acc = 0.f;
  for (int j = l; j < len; j += 64) {
    const int2 p = csr[beg + j];
    acc = fmaf(__int_as_float(p.y), H3[p.x], acc);
  }
#pragma unroll
  for (int off = 1; off < 64; off <<= 1) acc += __shfl_xor(acc, off, 64);
  if (l == 0) {
    const float dn = dinv[n];
    float t = dn * (acc + H3[n]) + b3[0];
    flat[n] = t > 0.f ? t : 0.f;
  }
}

// ================= final dense: out[b] += partial dot(flat, W_out[b,:]) =================
__global__ __launch_bounds__(256) void kfinal(const float* __restrict__ flat, const float* __restrict__ Wout,
                                              float* __restrict__ out) {
  const int b = blockIdx.x >> 2, q = blockIdx.x & 3;
  const float4* __restrict__ f4 = (const float4*)(flat) + q * 4096;
  const float4* __restrict__ w4 = (const float4*)(Wout + (size_t)b * NNODES) + q * 4096;
  float s = 0.f;
  for (int i = threadIdx.x; i < 4096; i += 256) {
    const float4 a = f4[i];
    const float4 wv = w4[i];
    s += a.x * wv.x + a.y * wv.y + a.z * wv.z + a.w * wv.w;
  }
#pragma unroll
  for (int off = 32; off; off >>= 1) s += __shfl_down(s, off, 64);
  __shared__ float red[4];
  if ((threadIdx.x & 63) == 0) red[threadIdx.x >> 6] = s;
  __syncthreads();
  if (threadIdx.x == 0) atomicAdd(&out[b], red[0] + red[1] + red[2] + red[3]);
}

extern "C" void kernel_launch(void* const* d_in, const int* in_sizes, int n_in,
                              void* d_out, int out_size, void* d_ws, size_t ws_size,
                              hipStream_t stream) {
  const float* x   = (const float*)d_in[0];
  const int*   A   = (const int*)d_in[1];
  const float* ew  = (const float*)d_in[2];
  const float* W1  = (const float*)d_in[3];
  const float* b1  = (const float*)d_in[4];
  const float* W2  = (const float*)d_in[5];
  const float* b2  = (const float*)d_in[6];
  const float* W3  = (const float*)d_in[7];
  const float* b3  = (const float*)d_in[8];
  const float* Wo  = (const float*)d_in[9];
  const float* bo  = (const float*)d_in[10];
  float* out = (float*)d_out;

  const int* src = A;
  const int* dst = A + NEDGES;

  // ---- workspace layout ----
  char* p = (char*)d_ws;
  float* dinv      = (float*)p; p += sizeof(float) * NNODES;
  int*   rsofs     = (int*)p;   p += sizeof(int) * NNODES;
  int*   cnt       = (int*)p;   p += sizeof(int) * NNODES;
  int*   counts    = (int*)p;   p += sizeof(int) * 256 * G;
  int*   bucketofs = (int*)p;   p += sizeof(int) * 260;
  int2*  tmp       = (int2*)p;  p += sizeof(int2) * NEDGES;
  int2*  csr       = (int2*)p;  p += sizeof(int2) * NEDGES;
  float* h1        = (float*)p; p += sizeof(float) * (size_t)NNODES * 16;
  float* H2        = (float*)p; p += sizeof(float) * (size_t)NNODES * 4;
  float* H3        = (float*)p; p += sizeof(float) * NNODES;
  float* flat      = (float*)p; p += sizeof(float) * NNODES;

  // ---- A: gemm ∪ hist (independent work, one launch) ----
  khistgemm<<<GEMMB + G, 512, 0, stream>>>(x, W1, h1, dst, counts);
  // ---- B: scatter (with redundant in-block scan) ----
  kscatter3<<<G, 1024, 0, stream>>>(src, dst, ew, counts, tmp, bucketofs);
  // ---- C: fine sort -> csr, rs, cnt, dinv ----
  ksortC<<<G, 512, 0, stream>>>(tmp, bucketofs, csr, rsofs, cnt, dinv);

  // ---- layers ----
  kgather1<<<NNODES / 4, 256, 0, stream>>>(h1, rsofs, cnt, csr, dinv, W2, b1, H2);
  kgather2<<<NNODES / 4, 256, 0, stream>>>(H2, rsofs, cnt, csr, dinv, W3, b2, H3);
  kgather3<<<NNODES / 4, 256, 0, stream>>>(H3, rsofs, cnt, csr, dinv, b3, flat, bo, out);
  kfinal<<<NB * 4, 256, 0, stream>>>(flat, Wo, out);
}